// Round 1
// baseline (786.503 us; speedup 1.0000x reference)
//
#include <hip/hip_runtime.h>

#define HID 64

// ---------- graph normalization ----------
__global__ void fill_deg(float* deg, int n) {
    int i = blockIdx.x * blockDim.x + threadIdx.x;
    if (i < n) deg[i] = 1.0f;  // self-loop
}

__global__ void deg_accum(const int* __restrict__ dst, float* deg, int E) {
    int e = blockIdx.x * blockDim.x + threadIdx.x;
    if (e < E) atomicAdd(&deg[dst[e]], 1.0f);
}

__global__ void dinv_kernel(float* deg, int n) {
    int i = blockIdx.x * blockDim.x + threadIdx.x;
    if (i < n) deg[i] = rsqrtf(fmaxf(deg[i], 1e-12f));
}

// ---------- input projection: h = x @ W_in + b_in ----------
__global__ void input_proj(const float* __restrict__ x, const float* __restrict__ Win,
                           const float* __restrict__ bin, float* __restrict__ h, int n) {
    int t = blockIdx.x * blockDim.x + threadIdx.x;
    int v = t >> 6, j = t & 63;
    if (v >= n) return;
    float acc = bin[j];
#pragma unroll
    for (int k = 0; k < 4; ++k) acc += x[v * 4 + k] * Win[k * 64 + j];
    h[t] = acc;
}

// ---------- per-layer GEMM + self-loop agg init ----------
// hw = h @ W ; agg = hw * dinv^2   (self-loop message pre-seeded, no memset needed)
__global__ void gemm_agg(const float* __restrict__ h, const float* __restrict__ W,
                         const float* __restrict__ dinv, float* __restrict__ hw,
                         float* __restrict__ agg, int n) {
    __shared__ float wl[64 * 64];
    __shared__ float hl[256];
    int tid = threadIdx.x;
#pragma unroll
    for (int i = 0; i < 16; ++i) wl[tid + 256 * i] = W[tid + 256 * i];
    int v = blockIdx.x * 4 + (tid >> 6);
    int j = tid & 63;
    bool valid = v < n;
    hl[tid] = valid ? h[(size_t)v * 64 + j] : 0.f;
    __syncthreads();
    if (!valid) return;
    const float* hr = &hl[(tid >> 6) << 6];  // broadcast reads (wave-uniform addr)
    float acc = 0.f;
#pragma unroll
    for (int k = 0; k < 64; ++k) acc += hr[k] * wl[k * 64 + j];  // 2-way bank alias: free
    float di = dinv[v];
    hw[(size_t)v * 64 + j] = acc;
    agg[(size_t)v * 64 + j] = acc * di * di;
}

// ---------- edge scatter: one wave per edge, lane = feature ----------
__global__ void scatter_edges(const int* __restrict__ eidx, const float* __restrict__ hw,
                              const float* __restrict__ dinv, float* __restrict__ agg, int E) {
    int t = blockIdx.x * blockDim.x + threadIdx.x;
    int e = t >> 6;
    if (e >= E) return;
    int j = t & 63;
    int s = eidx[e];       // wave-uniform
    int d = eidx[E + e];   // wave-uniform
    float val = hw[(size_t)s * 64 + j] * dinv[s] * dinv[d];
    atomicAdd(&agg[(size_t)d * 64 + j], val);
}

// ---------- conv bias + BN(eval) + ReLU + residual ----------
__global__ void finalize_layer(float* __restrict__ h, const float* __restrict__ agg,
                               const float* __restrict__ cb, const float* __restrict__ gamma,
                               const float* __restrict__ beta, const float* __restrict__ mean,
                               const float* __restrict__ var, int n) {
    int t = blockIdx.x * blockDim.x + threadIdx.x;
    if (t >= n * 64) return;
    int j = t & 63;
    float a = agg[t] + cb[j];
    a = (a - mean[j]) * rsqrtf(var[j] + 1e-5f) * gamma[j] + beta[j];
    a = fmaxf(a, 0.f);
    h[t] = a + h[t];  // residual: h still holds pre-conv value
}

// ---------- output MLP + autoregressive residual ----------
// out = x + relu(h@W1+b1) @ W2 + b2 ; one wave per node
__global__ void mlp_out(const float* __restrict__ h, const float* __restrict__ x,
                        const float* __restrict__ W1, const float* __restrict__ b1,
                        const float* __restrict__ W2, const float* __restrict__ b2,
                        float* __restrict__ out, int n) {
    __shared__ float wl[64 * 64];
    __shared__ float hl[256];
    int tid = threadIdx.x;
#pragma unroll
    for (int i = 0; i < 16; ++i) wl[tid + 256 * i] = W1[tid + 256 * i];
    int v = blockIdx.x * 4 + (tid >> 6);
    int j = tid & 63;
    bool valid = v < n;
    hl[tid] = valid ? h[(size_t)v * 64 + j] : 0.f;
    __syncthreads();
    float acc = b1[j];
    const float* hr = &hl[(tid >> 6) << 6];
#pragma unroll
    for (int k = 0; k < 64; ++k) acc += hr[k] * wl[k * 64 + j];
    float tj = fmaxf(acc, 0.f);
    float p0 = tj * W2[j * 4 + 0];
    float p1 = tj * W2[j * 4 + 1];
    float p2 = tj * W2[j * 4 + 2];
    float p3 = tj * W2[j * 4 + 3];
#pragma unroll
    for (int m = 32; m >= 1; m >>= 1) {  // 64-lane butterfly reduce
        p0 += __shfl_xor(p0, m, 64);
        p1 += __shfl_xor(p1, m, 64);
        p2 += __shfl_xor(p2, m, 64);
        p3 += __shfl_xor(p3, m, 64);
    }
    if (valid && j < 4) {
        float p = (j == 0) ? p0 : (j == 1) ? p1 : (j == 2) ? p2 : p3;
        out[v * 4 + j] = x[v * 4 + j] + p + b2[j];
    }
}

extern "C" void kernel_launch(void* const* d_in, const int* in_sizes, int n_in,
                              void* d_out, int out_size, void* d_ws, size_t ws_size,
                              hipStream_t stream) {
    const float* x     = (const float*)d_in[0];
    const int*   eidx  = (const int*)  d_in[1];
    const float* Win   = (const float*)d_in[2];
    const float* bin   = (const float*)d_in[3];
    const float* convw = (const float*)d_in[4];
    const float* convb = (const float*)d_in[5];
    const float* gamma = (const float*)d_in[6];
    const float* beta  = (const float*)d_in[7];
    const float* mean  = (const float*)d_in[8];
    const float* var   = (const float*)d_in[9];
    const float* W1    = (const float*)d_in[10];
    const float* b1    = (const float*)d_in[11];
    const float* W2    = (const float*)d_in[12];
    const float* b2    = (const float*)d_in[13];
    float* out = (float*)d_out;

    int n = in_sizes[0] / 4;   // 50000
    int E = in_sizes[1] / 2;   // 800000

    // workspace layout (floats): dinv | h | hw | agg   (~38.6 MB total)
    float* ws   = (float*)d_ws;
    size_t nh   = (size_t)n * 64;
    float* dinv = ws;
    float* h    = ws + (((size_t)n + 15) / 16) * 16;
    float* hw   = h + nh;
    float* agg  = hw + nh;

    const int B = 256;
    fill_deg<<<(n + B - 1) / B, B, 0, stream>>>(dinv, n);
    deg_accum<<<(E + B - 1) / B, B, 0, stream>>>(eidx + E, dinv, E);
    dinv_kernel<<<(n + B - 1) / B, B, 0, stream>>>(dinv, n);

    input_proj<<<(int)((nh + B - 1) / B), B, 0, stream>>>(x, Win, bin, h, n);

    for (int i = 0; i < 3; ++i) {
        gemm_agg<<<(n + 3) / 4, B, 0, stream>>>(h, convw + i * 4096, dinv, hw, agg, n);
        scatter_edges<<<(int)(((size_t)E * 64 + B - 1) / B), B, 0, stream>>>(eidx, hw, dinv, agg, E);
        finalize_layer<<<(int)((nh + B - 1) / B), B, 0, stream>>>(
            h, agg, convb + i * 64, gamma + i * 64, beta + i * 64, mean + i * 64, var + i * 64, n);
    }

    mlp_out<<<(n + 3) / 4, B, 0, stream>>>(h, x, W1, b1, W2, b2, out, n);
}

// Round 2
// 456.794 us; speedup vs baseline: 1.7218x; 1.7218x over previous
//
#include <hip/hip_runtime.h>

#define HID 64

// ================= CSR build =================
__global__ void zero2(int* counts, int* cursor, int n) {
    int i = blockIdx.x * blockDim.x + threadIdx.x;
    if (i < n) { counts[i] = 0; cursor[i] = 0; }
}

__global__ void hist_dst(const int* __restrict__ dst, int* counts, int E) {
    int e = blockIdx.x * blockDim.x + threadIdx.x;
    if (e < E) atomicAdd(&counts[dst[e]], 1);
}

// per-block inclusive scan of counts -> tmp; block totals -> bsum; also dinv
__global__ void scan1(const int* __restrict__ counts, int* __restrict__ tmp,
                      int* __restrict__ bsum, float* __restrict__ dinv, int n) {
    __shared__ int s[256];
    int t = threadIdx.x;
    int i = blockIdx.x * 256 + t;
    int v = (i < n) ? counts[i] : 0;
    if (i < n) dinv[i] = rsqrtf((float)v + 1.0f);  // deg incl. self-loop
    s[t] = v;
    __syncthreads();
#pragma unroll
    for (int d = 1; d < 256; d <<= 1) {
        int x = (t >= d) ? s[t - d] : 0;
        __syncthreads();
        s[t] += x;
        __syncthreads();
    }
    if (i < n) tmp[i] = s[t];
    if (t == 255) bsum[blockIdx.x] = s[255];
}

// exclusive scan of block sums (NB <= 256)
__global__ void scan2(const int* __restrict__ bsum, int* __restrict__ boff, int nb) {
    __shared__ int s[256];
    int t = threadIdx.x;
    s[t] = (t < nb) ? bsum[t] : 0;
    __syncthreads();
#pragma unroll
    for (int d = 1; d < 256; d <<= 1) {
        int x = (t >= d) ? s[t - d] : 0;
        __syncthreads();
        s[t] += x;
        __syncthreads();
    }
    if (t < nb) boff[t] = s[t] - bsum[t];  // exclusive
}

__global__ void scan3(const int* __restrict__ counts, const int* __restrict__ tmp,
                      const int* __restrict__ boff, int* __restrict__ rowptr, int n, int E) {
    int i = blockIdx.x * blockDim.x + threadIdx.x;
    if (i < n) rowptr[i] = tmp[i] - counts[i] + boff[blockIdx.x * 256 / 256 == 0 ? 0 : 0];  // placeholder
}

// (scan3 rewritten below correctly; kept single definition)
__global__ void scan3b(const int* __restrict__ counts, const int* __restrict__ tmp,
                       const int* __restrict__ boff, int* __restrict__ rowptr, int n, int E) {
    int b = blockIdx.x;
    int i = b * 256 + threadIdx.x;
    if (i < n) rowptr[i] = tmp[i] - counts[i] + boff[b];
    if (i == n - 1) rowptr[n] = tmp[i] + boff[b];  // == E
}

// bucket-fill CSR: col = src, ecoef = dinv[src]
__global__ void csr_fill(const int* __restrict__ eidx, const int* __restrict__ rowptr,
                         int* __restrict__ cursor, const float* __restrict__ dinv,
                         int* __restrict__ col, float* __restrict__ ecoef, int E) {
    int e = blockIdx.x * blockDim.x + threadIdx.x;
    if (e >= E) return;
    int s = eidx[e];
    int d = eidx[E + e];
    int pos = rowptr[d] + atomicAdd(&cursor[d], 1);
    col[pos] = s;
    ecoef[pos] = dinv[s];
}

// ================= dense ops =================
__global__ void input_proj(const float* __restrict__ x, const float* __restrict__ Win,
                           const float* __restrict__ bin, float* __restrict__ h, int n) {
    int t = blockIdx.x * blockDim.x + threadIdx.x;
    int v = t >> 6, j = t & 63;
    if (v >= n) return;
    float acc = bin[j];
#pragma unroll
    for (int k = 0; k < 4; ++k) acc += x[v * 4 + k] * Win[k * 64 + j];
    h[t] = acc;
}

// hw = h @ W  (4 nodes per 256-block, W staged in LDS)
__global__ void gemm64(const float* __restrict__ h, const float* __restrict__ W,
                       float* __restrict__ hw, int n) {
    __shared__ float wl[64 * 64];
    __shared__ float hl[256];
    int tid = threadIdx.x;
#pragma unroll
    for (int i = 0; i < 16; ++i) wl[tid + 256 * i] = W[tid + 256 * i];
    int v = blockIdx.x * 4 + (tid >> 6);
    int j = tid & 63;
    bool valid = v < n;
    hl[tid] = valid ? h[(size_t)v * 64 + j] : 0.f;
    __syncthreads();
    if (!valid) return;
    const float* hr = &hl[(tid >> 6) << 6];  // wave-uniform -> LDS broadcast
    float acc = 0.f;
#pragma unroll
    for (int k = 0; k < 64; ++k) acc += hr[k] * wl[k * 64 + j];  // 2-way alias: free
    hw[(size_t)v * 64 + j] = acc;
}

// pull aggregate + bias + BN(eval) + ReLU + residual, one wave per node
__global__ void gather_finalize(const int* __restrict__ rowptr, const int* __restrict__ col,
                                const float* __restrict__ ecoef, const float* __restrict__ hw,
                                const float* __restrict__ dinv, float* __restrict__ h,
                                const float* __restrict__ cb, const float* __restrict__ gamma,
                                const float* __restrict__ beta, const float* __restrict__ mean,
                                const float* __restrict__ var, int n) {
    int t = blockIdx.x * blockDim.x + threadIdx.x;
    int v = t >> 6;
    if (v >= n) return;
    int j = t & 63;
    int beg = rowptr[v], end = rowptr[v + 1];
    float di = dinv[v];
    float sum = hw[(size_t)v * 64 + j] * di;  // self-loop term (× di below)
    int e = beg;
    for (; e + 1 < end; e += 2) {  // 2-way ILP: both gathers issue before FMAs
        int s0 = col[e], s1 = col[e + 1];
        float c0 = ecoef[e], c1 = ecoef[e + 1];
        float v0 = hw[(size_t)s0 * 64 + j];
        float v1 = hw[(size_t)s1 * 64 + j];
        sum += v0 * c0;
        sum += v1 * c1;
    }
    if (e < end) sum += hw[(size_t)col[e] * 64 + j] * ecoef[e];
    float a = sum * di + cb[j];
    a = (a - mean[j]) * rsqrtf(var[j] + 1e-5f) * gamma[j] + beta[j];
    a = fmaxf(a, 0.f);
    h[t] = a + h[t];  // residual
}

// out = x + relu(h@W1+b1) @ W2 + b2 ; one wave per node
__global__ void mlp_out(const float* __restrict__ h, const float* __restrict__ x,
                        const float* __restrict__ W1, const float* __restrict__ b1,
                        const float* __restrict__ W2, const float* __restrict__ b2,
                        float* __restrict__ out, int n) {
    __shared__ float wl[64 * 64];
    __shared__ float hl[256];
    int tid = threadIdx.x;
#pragma unroll
    for (int i = 0; i < 16; ++i) wl[tid + 256 * i] = W1[tid + 256 * i];
    int v = blockIdx.x * 4 + (tid >> 6);
    int j = tid & 63;
    bool valid = v < n;
    hl[tid] = valid ? h[(size_t)v * 64 + j] : 0.f;
    __syncthreads();
    float acc = b1[j];
    const float* hr = &hl[(tid >> 6) << 6];
#pragma unroll
    for (int k = 0; k < 64; ++k) acc += hr[k] * wl[k * 64 + j];
    float tj = fmaxf(acc, 0.f);
    float p0 = tj * W2[j * 4 + 0];
    float p1 = tj * W2[j * 4 + 1];
    float p2 = tj * W2[j * 4 + 2];
    float p3 = tj * W2[j * 4 + 3];
#pragma unroll
    for (int m = 32; m >= 1; m >>= 1) {
        p0 += __shfl_xor(p0, m, 64);
        p1 += __shfl_xor(p1, m, 64);
        p2 += __shfl_xor(p2, m, 64);
        p3 += __shfl_xor(p3, m, 64);
    }
    if (valid && j < 4) {
        float p = (j == 0) ? p0 : (j == 1) ? p1 : (j == 2) ? p2 : p3;
        out[v * 4 + j] = x[v * 4 + j] + p + b2[j];
    }
}

extern "C" void kernel_launch(void* const* d_in, const int* in_sizes, int n_in,
                              void* d_out, int out_size, void* d_ws, size_t ws_size,
                              hipStream_t stream) {
    const float* x     = (const float*)d_in[0];
    const int*   eidx  = (const int*)  d_in[1];
    const float* Win   = (const float*)d_in[2];
    const float* bin   = (const float*)d_in[3];
    const float* convw = (const float*)d_in[4];
    const float* convb = (const float*)d_in[5];
    const float* gamma = (const float*)d_in[6];
    const float* beta  = (const float*)d_in[7];
    const float* mean  = (const float*)d_in[8];
    const float* var   = (const float*)d_in[9];
    const float* W1    = (const float*)d_in[10];
    const float* b1    = (const float*)d_in[11];
    const float* W2    = (const float*)d_in[12];
    const float* b2    = (const float*)d_in[13];
    float* out = (float*)d_out;

    int n = in_sizes[0] / 4;   // 50000
    int E = in_sizes[1] / 2;   // 800000
    const int B = 256;
    int NB = (n + B - 1) / B;  // 196 blocks for the scan

    // workspace layout (4B elems):
    // dinv[n] | h[n*64] | hw[n*64] | counts[n] | cursor[n] | tmp[n] |
    // rowptr[n+1] | bsum[256] | boff[256] | col[E] | ecoef[E]
    char* p = (char*)d_ws;
    size_t nh = (size_t)n * 64;
    float* dinv   = (float*)p;            p += ((size_t)n + 16) * 4;
    float* h      = (float*)p;            p += nh * 4;
    float* hw     = (float*)p;            p += nh * 4;
    int*   counts = (int*)p;              p += (size_t)n * 4;
    int*   cursor = (int*)p;              p += (size_t)n * 4;
    int*   tmp    = (int*)p;              p += (size_t)n * 4;
    int*   rowptr = (int*)p;              p += ((size_t)n + 16) * 4;
    int*   bsum   = (int*)p;              p += 256 * 4;
    int*   boff   = (int*)p;              p += 256 * 4;
    int*   col    = (int*)p;              p += (size_t)E * 4;
    float* ecoef  = (float*)p;            p += (size_t)E * 4;

    // ---- CSR build ----
    zero2<<<NB, B, 0, stream>>>(counts, cursor, n);
    hist_dst<<<(E + B - 1) / B, B, 0, stream>>>(eidx + E, counts, E);
    scan1<<<NB, B, 0, stream>>>(counts, tmp, bsum, dinv, n);
    scan2<<<1, B, 0, stream>>>(bsum, boff, NB);
    scan3b<<<NB, B, 0, stream>>>(counts, tmp, boff, rowptr, n, E);
    csr_fill<<<(E + B - 1) / B, B, 0, stream>>>(eidx, rowptr, cursor, dinv, col, ecoef, E);

    // ---- network ----
    input_proj<<<(int)((nh + B - 1) / B), B, 0, stream>>>(x, Win, bin, h, n);
    for (int i = 0; i < 3; ++i) {
        gemm64<<<(n + 3) / 4, B, 0, stream>>>(h, convw + i * 4096, hw, n);
        gather_finalize<<<(int)((nh + B - 1) / B), B, 0, stream>>>(
            rowptr, col, ecoef, hw, dinv, h,
            convb + i * 64, gamma + i * 64, beta + i * 64, mean + i * 64, var + i * 64, n);
    }
    mlp_out<<<(n + 3) / 4, B, 0, stream>>>(h, x, W1, b1, W2, b2, out, n);
}